// Round 18
// baseline (242.093 us; speedup 1.0000x reference)
//
#include <hip/hip_runtime.h>
#include <hip/hip_bf16.h>

typedef __bf16 bf16x8 __attribute__((ext_vector_type(8)));
typedef float f32x4 __attribute__((ext_vector_type(4)));

using bf = __hip_bfloat16;

constexpr int cB = 16, cH = 96, cW = 96, cC = 192;
constexpr int cT = cH * cW;       // 9216
constexpr int cM = cB * cT;       // 147456
constexpr int CH = 48;            // wkv chunk length
constexpr int NS = cT / CH;       // 192 chunks
constexpr int NTM = cM / 64;      // 2304 m-tiles
constexpr float Tinv = 1.0f / 9216.0f;

__device__ __forceinline__ int swz(int row, int bytecol) {
    return row * 384 + (bytecol ^ ((row & 7) << 4));
}
__device__ __forceinline__ float bflo(unsigned u) { return __uint_as_float(u << 16); }
__device__ __forceinline__ float bfhi(unsigned u) { return __uint_as_float(u & 0xffff0000u); }

// ---------------------------------------------------------------------------
// Pre-convert weights f32 -> bf16, concatenated rows: [Wk;Wv;Wr;Wo] (768x192)
// ---------------------------------------------------------------------------
__global__ __launch_bounds__(256) void convw_k(
    const float* __restrict__ Wk, const float* __restrict__ Wv,
    const float* __restrict__ Wr, const float* __restrict__ Wo,
    bf* __restrict__ out)
{
    int i = (blockIdx.x * 256 + threadIdx.x) * 8;
    int mat = i / 36864, off = i % 36864;
    const float* s = mat == 0 ? Wk : (mat == 1 ? Wv : (mat == 2 ? Wr : Wo));
    const float4* sp = reinterpret_cast<const float4*>(s + off);
    float4 a0 = sp[0], a1 = sp[1];
    bf16x8 pk;
    pk[0]=(__bf16)a0.x; pk[1]=(__bf16)a0.y; pk[2]=(__bf16)a0.z; pk[3]=(__bf16)a0.w;
    pk[4]=(__bf16)a1.x; pk[5]=(__bf16)a1.y; pk[6]=(__bf16)a1.z; pk[7]=(__bf16)a1.w;
    *reinterpret_cast<bf16x8*>(reinterpret_cast<__bf16*>(out) + i) = pk;
}

// ---------------------------------------------------------------------------
// gemm0f (223us-champion form): fused 3-matrix GEMM. Grid 256, 768 thr = 12
// waves; wave wid: mat = wid>>2, strip = wid&3. B fragments (own mat)
// persistent in registers; A double-buffered in LDS (2 x 24KB); per step:
// issue A-loads(i+1) -> compute(i) -> store -> ds_write(i+1) -> one barrier.
// x read once (FETCH 65MB verified); scalar [m][c] stores (WRITE 166MB clean).
// NOTE: 12 waves + VGPR 80 -> 1 block/CU structurally (16-wave band);
// measured ~95us, ~2.5 TB/s = that regime's ceiling.
// ---------------------------------------------------------------------------
__global__ __launch_bounds__(768, 3) void gemm0f(
    const float* __restrict__ Ap, const bf* __restrict__ Wb,
    bf* __restrict__ O0, bf* __restrict__ O1, bf* __restrict__ O2)
{
    __shared__ char lds[2 * 64 * 384];
    const int tid = threadIdx.x, bx = blockIdx.x;
    const int lane = tid & 63, wid = tid >> 6;
    const int mat = wid >> 2, strip = wid & 3;
    const int lr = lane & 15, lq = lane >> 4;

    bf16x8 bw[3][6];
    {
        const bf* Wt = Wb + (size_t)mat * 192 * cC;
#pragma unroll
        for (int nt = 0; nt < 3; ++nt)
#pragma unroll
            for (int kk = 0; kk < 6; ++kk)
                bw[nt][kk] = *reinterpret_cast<const bf16x8*>(
                    Wt + (size_t)(strip * 48 + nt * 16 + lr) * cC + kk * 32 + lq * 8);
    }

    int rj[2], kbj[2];
#pragma unroll
    for (int j = 0; j < 2; ++j) { int idx = tid + j * 768; rj[j] = idx / 24; kbj[j] = idx % 24; }

    float4 pfA[4];

    auto loadA = [&](int tile) {
#pragma unroll
        for (int j = 0; j < 2; ++j) {
            int gm = tile * 64 + rj[j];
            int b = gm / cT, t = gm % cT, h = t / cW, w = t % cW;
            int grp = kbj[j] / 6;
            int hs = h + (grp == 2 ? -1 : (grp == 3 ? 1 : 0));
            int ws2 = w + (grp == 0 ? -1 : (grp == 1 ? 1 : 0));
            pfA[2*j] = float4{0,0,0,0}; pfA[2*j+1] = float4{0,0,0,0};
            if (hs >= 0 && hs < cH && ws2 >= 0 && ws2 < cW) {
                const float4* s = reinterpret_cast<const float4*>(
                    Ap + ((size_t)b * cT + (size_t)hs * cW + ws2) * cC + kbj[j] * 8);
                pfA[2*j] = s[0]; pfA[2*j+1] = s[1];
            }
        }
    };
    auto writeA = [&](int bufIdx) {
        char* An = &lds[0] + bufIdx * (64 * 384);
#pragma unroll
        for (int j = 0; j < 2; ++j) {
            bf16x8 pk;
            pk[0]=(__bf16)pfA[2*j].x; pk[1]=(__bf16)pfA[2*j].y; pk[2]=(__bf16)pfA[2*j].z; pk[3]=(__bf16)pfA[2*j].w;
            pk[4]=(__bf16)pfA[2*j+1].x; pk[5]=(__bf16)pfA[2*j+1].y; pk[6]=(__bf16)pfA[2*j+1].z; pk[7]=(__bf16)pfA[2*j+1].w;
            *reinterpret_cast<bf16x8*>(An + swz(rj[j], kbj[j] * 16)) = pk;
        }
    };

    bf* Os = (mat == 0 ? O0 : (mat == 1 ? O1 : O2));

    loadA(bx); writeA(0);
    __syncthreads();

    for (int i = 0; i < 9; ++i) {
        const int tix = bx + 256 * i;
        if (i < 8) loadA(bx + 256 * (i + 1));
        char* Ab = &lds[0] + (i & 1) * (64 * 384);
#pragma unroll
        for (int mh = 0; mh < 2; ++mh) {
            f32x4 acc[2][3] = {};
#pragma unroll
            for (int kk = 0; kk < 6; ++kk) {
                const int bc = kk * 64 + lq * 16;
                bf16x8 af[2];
#pragma unroll
                for (int mt = 0; mt < 2; ++mt)
                    af[mt] = *reinterpret_cast<const bf16x8*>(
                        Ab + swz(mh * 32 + mt * 16 + lr, bc));
#pragma unroll
                for (int mt = 0; mt < 2; ++mt)
#pragma unroll
                    for (int nt = 0; nt < 3; ++nt)
                        acc[mt][nt] = __builtin_amdgcn_mfma_f32_16x16x32_bf16(
                            af[mt], bw[nt][kk], acc[mt][nt], 0, 0, 0);
            }
#pragma unroll
            for (int mt = 0; mt < 2; ++mt)
#pragma unroll
                for (int nt = 0; nt < 3; ++nt)
#pragma unroll
                    for (int j = 0; j < 4; ++j) {
                        int row = tix * 64 + mh * 32 + mt * 16 + lq * 4 + j;
                        int col = strip * 48 + nt * 16 + lr;
                        float v = acc[mt][nt][j];
                        if (mat == 2) v = 1.0f / (1.0f + __expf(-v));
                        Os[(size_t)row * cC + col] = __float2bfloat16(v);
                    }
        }
        if (i < 8) writeA((i + 1) & 1);
        __syncthreads();
    }
}

// ---------------------------------------------------------------------------
// gemm1f v2: out = z @ Wo^T.  256 thr = 4 waves (wave wn = one 48-col strip),
// grid 1024 -> 4 blocks/CU (16 waves, 4 independent barrier groups).
// B (Wo) fragments persistent in registers (72 VGPR); LDS = single 24KB A buf.
// Per tile: ds_write(prefetched regs) | barrier | issue loads(next tile)
// | compute (4 x 16-row sub-tiles, acc[3] each) + scalar f32 stores | barrier.
// ---------------------------------------------------------------------------
__global__ __launch_bounds__(256, 4) void gemm1f(
    const bf* __restrict__ Az, const bf* __restrict__ Wb,
    float* __restrict__ Out)
{
    __shared__ char lds[64 * 384];
    char* Ab = &lds[0];
    const int tid = threadIdx.x, bx = blockIdx.x;
    const int lane = tid & 63, wn = tid >> 6;   // 4 waves = 4 col strips
    const int lr = lane & 15, lq = lane >> 4;

    bf16x8 bw[3][6];
#pragma unroll
    for (int nt = 0; nt < 3; ++nt)
#pragma unroll
        for (int kk = 0; kk < 6; ++kk)
            bw[nt][kk] = *reinterpret_cast<const bf16x8*>(
                Wb + (size_t)(wn * 48 + nt * 16 + lr) * cC + kk * 32 + lq * 8);

    // A staging coords: 64*24 = 1536 chunks, 6 per thread
    int rj[6], kbj[6];
#pragma unroll
    for (int j = 0; j < 6; ++j) { int idx = tid + j * 256; rj[j] = idx / 24; kbj[j] = idx % 24; }

    int4 piA[6];
    auto loadA = [&](int tile) {
#pragma unroll
        for (int j = 0; j < 6; ++j)
            piA[j] = *reinterpret_cast<const int4*>(
                Az + (size_t)(tile * 64 + rj[j]) * cC + kbj[j] * 8);
    };

    loadA(bx);
    for (int tix = bx; tix < NTM; tix += 1024) {
#pragma unroll
        for (int j = 0; j < 6; ++j)
            *reinterpret_cast<int4*>(Ab + swz(rj[j], kbj[j] * 16)) = piA[j];
        __syncthreads();
        if (tix + 1024 < NTM) loadA(tix + 1024);   // lands during compute
#pragma unroll
        for (int mh = 0; mh < 4; ++mh) {            // 16-row sub-tiles
            f32x4 acc[3] = {};
#pragma unroll
            for (int kk = 0; kk < 6; ++kk) {
                const int bc = kk * 64 + lq * 16;
                bf16x8 af = *reinterpret_cast<const bf16x8*>(
                    Ab + swz(mh * 16 + lr, bc));
#pragma unroll
                for (int nt = 0; nt < 3; ++nt)
                    acc[nt] = __builtin_amdgcn_mfma_f32_16x16x32_bf16(
                        af, bw[nt][kk], acc[nt], 0, 0, 0);
            }
#pragma unroll
            for (int nt = 0; nt < 3; ++nt)
#pragma unroll
                for (int j = 0; j < 4; ++j) {
                    int row = tix * 64 + mh * 16 + lq * 4 + j;
                    int col = wn * 48 + nt * 16 + lr;
                    Out[(size_t)row * cC + col] = acc[nt][j];
                }
        }
        __syncthreads();
    }
}

// ---------------------------------------------------------------------------
// WKV (R8/R14-proven): chunked scan over [m][c] bf16, 2 channels/thread,
// CH=48 (NS=192), per-step software prefetch, in-place pass2.
// ---------------------------------------------------------------------------
__global__ __launch_bounds__(192) void wkv_pass1(
    const bf* __restrict__ k, const bf* __restrict__ v,
    const float* __restrict__ sd,
    float* __restrict__ stP, float* __restrict__ stQ, float* __restrict__ stO)
{
    const int c2 = threadIdx.x % 96, sub = threadIdx.x / 96;
    const int b = blockIdx.y, ch = blockIdx.x * 2 + sub;
    const int c0 = c2 * 2;
    const float w0 = sd[c0] * Tinv, w1 = sd[c0 + 1] * Tinv;
    size_t base = ((size_t)b * cT + (size_t)ch * CH) * cC + c0;
    float p0 = 0.f, q0 = 0.f, o0 = -1e38f;
    float p1 = 0.f, q1 = 0.f, o1 = -1e38f;
    unsigned kwc = *reinterpret_cast<const unsigned*>(k + base);
    unsigned vwc = *reinterpret_cast<const unsigned*>(v + base);
    for (int s = 0; s < CH; ++s) {
        unsigned kwn = 0, vwn = 0;
        if (s + 1 < CH) {
            kwn = *reinterpret_cast<const unsigned*>(k + base + (size_t)(s + 1) * cC);
            vwn = *reinterpret_cast<const unsigned*>(v + base + (size_t)(s + 1) * cC);
        }
        float kt0 = bflo(kwc), kt1 = bfhi(kwc);
        float vt0 = bflo(vwc), vt1 = bfhi(vwc);
        float no0 = fmaxf(w0 + o0, kt0);
        float A0 = __expf(w0 + o0 - no0), B0 = __expf(kt0 - no0);
        p0 = A0 * p0 + B0 * vt0; q0 = A0 * q0 + B0; o0 = no0;
        float no1 = fmaxf(w1 + o1, kt1);
        float A1 = __expf(w1 + o1 - no1), B1 = __expf(kt1 - no1);
        p1 = A1 * p1 + B1 * vt1; q1 = A1 * q1 + B1; o1 = no1;
        kwc = kwn; vwc = vwn;
    }
    size_t si = ((size_t)b * NS + ch) * cC + c0;
    *reinterpret_cast<float2*>(stP + si) = make_float2(p0, p1);
    *reinterpret_cast<float2*>(stQ + si) = make_float2(q0, q1);
    *reinterpret_cast<float2*>(stO + si) = make_float2(o0, o1);
}

// In-place exclusive prefix over chunk states.
__global__ __launch_bounds__(192) void wkv_pass2(
    float* __restrict__ stP, float* __restrict__ stQ, float* __restrict__ stO,
    const float* __restrict__ sd)
{
    const int c = threadIdx.x, b = blockIdx.x;
    const float w = sd[c] * Tinv;
    const float Lw = w * (float)CH;
    float p = 0.f, q = 0.f, o = -1e38f;
    size_t si = (size_t)b * NS * cC + c;
    float sp = stP[si], sq = stQ[si], so = stO[si];
    for (int ch = 0; ch < NS; ++ch) {
        float np_ = 0.f, nq_ = 0.f, no_ = -1e38f;
        if (ch + 1 < NS) {
            size_t sj = si + (size_t)(ch + 1) * cC;
            np_ = stP[sj]; nq_ = stQ[sj]; no_ = stO[sj];
        }
        size_t sc = si + (size_t)ch * cC;
        stP[sc] = p; stQ[sc] = q; stO[sc] = o;
        float po = o + Lw;
        float m = fmaxf(po, so);
        float e1 = __expf(po - m), e2 = __expf(so - m);
        p = e1 * p + e2 * sp;
        q = e1 * q + e2 * sq;
        o = m;
        sp = np_; sq = nq_; so = no_;
    }
}

__global__ __launch_bounds__(192) void wkv_pass3(
    const bf* __restrict__ k, const bf* __restrict__ v, const bf* __restrict__ sr,
    const float* __restrict__ sd, const float* __restrict__ sf,
    const float* __restrict__ iP, const float* __restrict__ iQ,
    const float* __restrict__ iO, bf* __restrict__ z)
{
    const int c2 = threadIdx.x % 96, sub = threadIdx.x / 96;
    const int b = blockIdx.y, ch = blockIdx.x * 2 + sub;
    const int c0 = c2 * 2;
    const float w0 = sd[c0] * Tinv, w1 = sd[c0 + 1] * Tinv;
    const float u0 = sf[c0] * Tinv, u1 = sf[c0 + 1] * Tinv;
    size_t si = ((size_t)b * NS + ch) * cC + c0;
    float2 pp = *reinterpret_cast<const float2*>(iP + si);
    float2 qq = *reinterpret_cast<const float2*>(iQ + si);
    float2 oo = *reinterpret_cast<const float2*>(iO + si);
    float p0 = pp.x, q0 = qq.x, o0 = oo.x;
    float p1 = pp.y, q1 = qq.y, o1 = oo.y;
    size_t base = ((size_t)b * cT + (size_t)ch * CH) * cC + c0;
    unsigned kwc = *reinterpret_cast<const unsigned*>(k + base);
    unsigned vwc = *reinterpret_cast<const unsigned*>(v + base);
    unsigned rwc = *reinterpret_cast<const unsigned*>(sr + base);
    for (int s = 0; s < CH; ++s) {
        unsigned kwn = 0, vwn = 0, rwn = 0;
        if (s + 1 < CH) {
            size_t nx = base + (size_t)(s + 1) * cC;
            kwn = *reinterpret_cast<const unsigned*>(k + nx);
            vwn = *reinterpret_cast<const unsigned*>(v + nx);
            rwn = *reinterpret_cast<const unsigned*>(sr + nx);
        }
        float kt0 = bflo(kwc), kt1 = bfhi(kwc);
        float vt0 = bflo(vwc), vt1 = bfhi(vwc);
        float rt0 = bflo(rwc), rt1 = bfhi(rwc);

        float no0 = fmaxf(o0, u0 + kt0);
        float Ae0 = __expf(o0 - no0), Be0 = __expf(u0 + kt0 - no0);
        float y0 = (Ae0 * p0 + Be0 * vt0) / (Ae0 * q0 + Be0);
        float no1 = fmaxf(o1, u1 + kt1);
        float Ae1 = __expf(o1 - no1), Be1 = __expf(u1 + kt1 - no1);
        float y1 = (Ae1 * p1 + Be1 * vt1) / (Ae1 * q1 + Be1);

        bf z0 = __float2bfloat16(rt0 * y0);
        bf z1 = __float2bfloat16(rt1 * y1);
        unsigned zp = (unsigned)*reinterpret_cast<unsigned short*>(&z0)
                    | ((unsigned)*reinterpret_cast<unsigned short*>(&z1) << 16);
        *reinterpret_cast<unsigned*>(z + base + (size_t)s * cC) = zp;

        float m0 = fmaxf(w0 + o0, kt0);
        float A0 = __expf(w0 + o0 - m0), B0 = __expf(kt0 - m0);
        p0 = A0 * p0 + B0 * vt0; q0 = A0 * q0 + B0; o0 = m0;
        float m1 = fmaxf(w1 + o1, kt1);
        float A1 = __expf(w1 + o1 - m1), B1 = __expf(kt1 - m1);
        p1 = A1 * p1 + B1 * vt1; q1 = A1 * q1 + B1; o1 = m1;
        kwc = kwn; vwc = vwn; rwc = rwn;
    }
}

extern "C" void kernel_launch(void* const* d_in, const int* in_sizes, int n_in,
                              void* d_out, int out_size, void* d_ws, size_t ws_size,
                              hipStream_t stream)
{
    const float* x  = (const float*)d_in[0];
    const float* Wk = (const float*)d_in[1];
    const float* Wv = (const float*)d_in[2];
    const float* Wr = (const float*)d_in[3];
    const float* Wo = (const float*)d_in[4];
    const float* sd = (const float*)d_in[5];
    const float* sf = (const float*)d_in[6];
    float* out = (float*)d_out;

    const size_t nEl = (size_t)cM * cC;          // 28,311,552 elements
    // d_out (f32, 113.2MB) holds k and sr (bf16, 2x56.6MB) until final gemm.
    bf* kbuf  = (bf*)d_out;
    bf* srbuf = (bf*)d_out + nEl;
    char* ws = (char*)d_ws;
    bf* vbuf = (bf*)ws;                           // 56.6MB
    bf* zbuf = (bf*)(ws + 2 * nEl);               // 56.6MB
    const size_t stN = (size_t)cB * NS * cC;      // 589,824 floats each
    float* stP = (float*)(ws + 4 * nEl);          // 3 x 2.36MB (in-place prefix)
    float* stQ = stP + stN;
    float* stO = stQ + stN;
    bf* wbf = (bf*)(stO + stN);                   // [Wk;Wv;Wr;Wo] bf16, 768x192

    convw_k<<<dim3(72), dim3(256), 0, stream>>>(Wk, Wv, Wr, Wo, wbf);
    gemm0f<<<dim3(256), dim3(768), 0, stream>>>(x, wbf, kbuf, vbuf, srbuf);
    wkv_pass1<<<dim3(NS / 2, cB), dim3(192), 0, stream>>>(kbuf, vbuf, sd, stP, stQ, stO);
    wkv_pass2<<<dim3(cB), dim3(192), 0, stream>>>(stP, stQ, stO, sd);
    wkv_pass3<<<dim3(NS / 2, cB), dim3(192), 0, stream>>>(
        kbuf, vbuf, srbuf, sd, sf, stP, stQ, stO, zbuf);
    gemm1f<<<dim3(1024), dim3(256), 0, stream>>>(
        zbuf, wbf + (size_t)576 * cC, out);
}

// Round 19
// 227.527 us; speedup vs baseline: 1.0640x; 1.0640x over previous
//
#include <hip/hip_runtime.h>
#include <hip/hip_bf16.h>

typedef __bf16 bf16x8 __attribute__((ext_vector_type(8)));
typedef float f32x4 __attribute__((ext_vector_type(4)));

using bf = __hip_bfloat16;

constexpr int cB = 16, cH = 96, cW = 96, cC = 192;
constexpr int cT = cH * cW;       // 9216
constexpr int cM = cB * cT;       // 147456
constexpr int CH = 48;            // wkv chunk length
constexpr int NS = cT / CH;       // 192 chunks
constexpr float Tinv = 1.0f / 9216.0f;

__device__ __forceinline__ int swz(int row, int bytecol) {
    return row * 384 + (bytecol ^ ((row & 7) << 4));
}
__device__ __forceinline__ float bflo(unsigned u) { return __uint_as_float(u << 16); }
__device__ __forceinline__ float bfhi(unsigned u) { return __uint_as_float(u & 0xffff0000u); }

// ---------------------------------------------------------------------------
// Pre-convert weights f32 -> bf16, concatenated rows: [Wk;Wv;Wr;Wo] (768x192)
// ---------------------------------------------------------------------------
__global__ __launch_bounds__(256) void convw_k(
    const float* __restrict__ Wk, const float* __restrict__ Wv,
    const float* __restrict__ Wr, const float* __restrict__ Wo,
    bf* __restrict__ out)
{
    int i = (blockIdx.x * 256 + threadIdx.x) * 8;
    int mat = i / 36864, off = i % 36864;
    const float* s = mat == 0 ? Wk : (mat == 1 ? Wv : (mat == 2 ? Wr : Wo));
    const float4* sp = reinterpret_cast<const float4*>(s + off);
    float4 a0 = sp[0], a1 = sp[1];
    bf16x8 pk;
    pk[0]=(__bf16)a0.x; pk[1]=(__bf16)a0.y; pk[2]=(__bf16)a0.z; pk[3]=(__bf16)a0.w;
    pk[4]=(__bf16)a1.x; pk[5]=(__bf16)a1.y; pk[6]=(__bf16)a1.z; pk[7]=(__bf16)a1.w;
    *reinterpret_cast<bf16x8*>(reinterpret_cast<__bf16*>(out) + i) = pk;
}

// ---------------------------------------------------------------------------
// gemm0f (223us-champion form): fused 3-matrix GEMM. Grid 256, 768 thr = 12
// waves; wave wid: mat = wid>>2, strip = wid&3. B fragments (own mat)
// persistent in registers; A double-buffered in LDS (2 x 24KB); per step:
// issue A-loads(i+1) -> compute(i) -> store -> ds_write(i+1) -> one barrier.
// x read once (FETCH 65MB verified); scalar [m][c] stores (WRITE 166MB clean).
// Measured ~94-95us @ 2.5 TB/s (1 block/CU regime ceiling).
// ---------------------------------------------------------------------------
__global__ __launch_bounds__(768, 3) void gemm0f(
    const float* __restrict__ Ap, const bf* __restrict__ Wb,
    bf* __restrict__ O0, bf* __restrict__ O1, bf* __restrict__ O2)
{
    __shared__ char lds[2 * 64 * 384];
    const int tid = threadIdx.x, bx = blockIdx.x;
    const int lane = tid & 63, wid = tid >> 6;
    const int mat = wid >> 2, strip = wid & 3;
    const int lr = lane & 15, lq = lane >> 4;

    bf16x8 bw[3][6];
    {
        const bf* Wt = Wb + (size_t)mat * 192 * cC;
#pragma unroll
        for (int nt = 0; nt < 3; ++nt)
#pragma unroll
            for (int kk = 0; kk < 6; ++kk)
                bw[nt][kk] = *reinterpret_cast<const bf16x8*>(
                    Wt + (size_t)(strip * 48 + nt * 16 + lr) * cC + kk * 32 + lq * 8);
    }

    int rj[2], kbj[2];
#pragma unroll
    for (int j = 0; j < 2; ++j) { int idx = tid + j * 768; rj[j] = idx / 24; kbj[j] = idx % 24; }

    float4 pfA[4];

    auto loadA = [&](int tile) {
#pragma unroll
        for (int j = 0; j < 2; ++j) {
            int gm = tile * 64 + rj[j];
            int b = gm / cT, t = gm % cT, h = t / cW, w = t % cW;
            int grp = kbj[j] / 6;
            int hs = h + (grp == 2 ? -1 : (grp == 3 ? 1 : 0));
            int ws2 = w + (grp == 0 ? -1 : (grp == 1 ? 1 : 0));
            pfA[2*j] = float4{0,0,0,0}; pfA[2*j+1] = float4{0,0,0,0};
            if (hs >= 0 && hs < cH && ws2 >= 0 && ws2 < cW) {
                const float4* s = reinterpret_cast<const float4*>(
                    Ap + ((size_t)b * cT + (size_t)hs * cW + ws2) * cC + kbj[j] * 8);
                pfA[2*j] = s[0]; pfA[2*j+1] = s[1];
            }
        }
    };
    auto writeA = [&](int bufIdx) {
        char* An = &lds[0] + bufIdx * (64 * 384);
#pragma unroll
        for (int j = 0; j < 2; ++j) {
            bf16x8 pk;
            pk[0]=(__bf16)pfA[2*j].x; pk[1]=(__bf16)pfA[2*j].y; pk[2]=(__bf16)pfA[2*j].z; pk[3]=(__bf16)pfA[2*j].w;
            pk[4]=(__bf16)pfA[2*j+1].x; pk[5]=(__bf16)pfA[2*j+1].y; pk[6]=(__bf16)pfA[2*j+1].z; pk[7]=(__bf16)pfA[2*j+1].w;
            *reinterpret_cast<bf16x8*>(An + swz(rj[j], kbj[j] * 16)) = pk;
        }
    };

    bf* Os = (mat == 0 ? O0 : (mat == 1 ? O1 : O2));

    loadA(bx); writeA(0);
    __syncthreads();

    for (int i = 0; i < 9; ++i) {
        const int tix = bx + 256 * i;
        if (i < 8) loadA(bx + 256 * (i + 1));
        char* Ab = &lds[0] + (i & 1) * (64 * 384);
#pragma unroll
        for (int mh = 0; mh < 2; ++mh) {
            f32x4 acc[2][3] = {};
#pragma unroll
            for (int kk = 0; kk < 6; ++kk) {
                const int bc = kk * 64 + lq * 16;
                bf16x8 af[2];
#pragma unroll
                for (int mt = 0; mt < 2; ++mt)
                    af[mt] = *reinterpret_cast<const bf16x8*>(
                        Ab + swz(mh * 32 + mt * 16 + lr, bc));
#pragma unroll
                for (int mt = 0; mt < 2; ++mt)
#pragma unroll
                    for (int nt = 0; nt < 3; ++nt)
                        acc[mt][nt] = __builtin_amdgcn_mfma_f32_16x16x32_bf16(
                            af[mt], bw[nt][kk], acc[mt][nt], 0, 0, 0);
            }
#pragma unroll
            for (int mt = 0; mt < 2; ++mt)
#pragma unroll
                for (int nt = 0; nt < 3; ++nt)
#pragma unroll
                    for (int j = 0; j < 4; ++j) {
                        int row = tix * 64 + mh * 32 + mt * 16 + lq * 4 + j;
                        int col = strip * 48 + nt * 16 + lr;
                        float v = acc[mt][nt][j];
                        if (mat == 2) v = 1.0f / (1.0f + __expf(-v));
                        Os[(size_t)row * cC + col] = __float2bfloat16(v);
                    }
        }
        if (i < 8) writeA((i + 1) & 1);
        __syncthreads();
    }
}

// ---------------------------------------------------------------------------
// gemm1g: out = z @ Wo^T in gemm0f's EXACT skeleton (the 2.5 TB/s structure).
// Grid 256 persistent, 768 thr = 12 waves arranged 4m x 3n (wave = 16 rows x
// 64 cols). Wo entirely in registers (24 frags = 96 VGPR/wave). A (z bf16)
// double-buffered 2x24KB; per step: issue A-loads(i+1) -> compute(i) ->
// f32 stores -> ds_write(i+1) -> one barrier. 9 steps.
// ---------------------------------------------------------------------------
__global__ __launch_bounds__(768, 3) void gemm1g(
    const bf* __restrict__ Az, const bf* __restrict__ Wb,
    float* __restrict__ Out)
{
    __shared__ char lds[2 * 64 * 384];
    const int tid = threadIdx.x, bx = blockIdx.x;
    const int lane = tid & 63, wid = tid >> 6;
    const int wm = wid >> 2;          // 0..2? NO: 12 waves -> wm = wid/3
    const int wmm = wid / 3, wn = wid % 3;   // 4m x 3n
    const int lr = lane & 15, lq = lane >> 4;
    (void)wm;

    bf16x8 bw[4][6];
#pragma unroll
    for (int nt = 0; nt < 4; ++nt)
#pragma unroll
        for (int kk = 0; kk < 6; ++kk)
            bw[nt][kk] = *reinterpret_cast<const bf16x8*>(
                Wb + (size_t)(wn * 64 + nt * 16 + lr) * cC + kk * 32 + lq * 8);

    int rj[2], kbj[2];
#pragma unroll
    for (int j = 0; j < 2; ++j) { int idx = tid + j * 768; rj[j] = idx / 24; kbj[j] = idx % 24; }

    int4 piA[2];
    auto loadA = [&](int tile) {
#pragma unroll
        for (int j = 0; j < 2; ++j)
            piA[j] = *reinterpret_cast<const int4*>(
                Az + (size_t)(tile * 64 + rj[j]) * cC + kbj[j] * 8);
    };
    auto writeA = [&](int bufIdx) {
        char* An = &lds[0] + bufIdx * (64 * 384);
#pragma unroll
        for (int j = 0; j < 2; ++j)
            *reinterpret_cast<int4*>(An + swz(rj[j], kbj[j] * 16)) = piA[j];
    };

    loadA(bx); writeA(0);
    __syncthreads();

    for (int i = 0; i < 9; ++i) {
        const int tix = bx + 256 * i;
        if (i < 8) loadA(bx + 256 * (i + 1));
        char* Ab = &lds[0] + (i & 1) * (64 * 384);
        f32x4 acc[4] = {};
#pragma unroll
        for (int kk = 0; kk < 6; ++kk) {
            const int bc = kk * 64 + lq * 16;
            bf16x8 af = *reinterpret_cast<const bf16x8*>(
                Ab + swz(wmm * 16 + lr, bc));
#pragma unroll
            for (int nt = 0; nt < 4; ++nt)
                acc[nt] = __builtin_amdgcn_mfma_f32_16x16x32_bf16(
                    af, bw[nt][kk], acc[nt], 0, 0, 0);
        }
#pragma unroll
        for (int nt = 0; nt < 4; ++nt)
#pragma unroll
            for (int j = 0; j < 4; ++j) {
                int row = tix * 64 + wmm * 16 + lq * 4 + j;
                int col = wn * 64 + nt * 16 + lr;
                Out[(size_t)row * cC + col] = acc[nt][j];
            }
        if (i < 8) writeA((i + 1) & 1);
        __syncthreads();
    }
}

// ---------------------------------------------------------------------------
// WKV (R8/R14-proven): chunked scan over [m][c] bf16, 2 channels/thread,
// CH=48 (NS=192), per-step software prefetch, in-place pass2.
// ---------------------------------------------------------------------------
__global__ __launch_bounds__(192) void wkv_pass1(
    const bf* __restrict__ k, const bf* __restrict__ v,
    const float* __restrict__ sd,
    float* __restrict__ stP, float* __restrict__ stQ, float* __restrict__ stO)
{
    const int c2 = threadIdx.x % 96, sub = threadIdx.x / 96;
    const int b = blockIdx.y, ch = blockIdx.x * 2 + sub;
    const int c0 = c2 * 2;
    const float w0 = sd[c0] * Tinv, w1 = sd[c0 + 1] * Tinv;
    size_t base = ((size_t)b * cT + (size_t)ch * CH) * cC + c0;
    float p0 = 0.f, q0 = 0.f, o0 = -1e38f;
    float p1 = 0.f, q1 = 0.f, o1 = -1e38f;
    unsigned kwc = *reinterpret_cast<const unsigned*>(k + base);
    unsigned vwc = *reinterpret_cast<const unsigned*>(v + base);
    for (int s = 0; s < CH; ++s) {
        unsigned kwn = 0, vwn = 0;
        if (s + 1 < CH) {
            kwn = *reinterpret_cast<const unsigned*>(k + base + (size_t)(s + 1) * cC);
            vwn = *reinterpret_cast<const unsigned*>(v + base + (size_t)(s + 1) * cC);
        }
        float kt0 = bflo(kwc), kt1 = bfhi(kwc);
        float vt0 = bflo(vwc), vt1 = bfhi(vwc);
        float no0 = fmaxf(w0 + o0, kt0);
        float A0 = __expf(w0 + o0 - no0), B0 = __expf(kt0 - no0);
        p0 = A0 * p0 + B0 * vt0; q0 = A0 * q0 + B0; o0 = no0;
        float no1 = fmaxf(w1 + o1, kt1);
        float A1 = __expf(w1 + o1 - no1), B1 = __expf(kt1 - no1);
        p1 = A1 * p1 + B1 * vt1; q1 = A1 * q1 + B1; o1 = no1;
        kwc = kwn; vwc = vwn;
    }
    size_t si = ((size_t)b * NS + ch) * cC + c0;
    *reinterpret_cast<float2*>(stP + si) = make_float2(p0, p1);
    *reinterpret_cast<float2*>(stQ + si) = make_float2(q0, q1);
    *reinterpret_cast<float2*>(stO + si) = make_float2(o0, o1);
}

// In-place exclusive prefix over chunk states.
__global__ __launch_bounds__(192) void wkv_pass2(
    float* __restrict__ stP, float* __restrict__ stQ, float* __restrict__ stO,
    const float* __restrict__ sd)
{
    const int c = threadIdx.x, b = blockIdx.x;
    const float w = sd[c] * Tinv;
    const float Lw = w * (float)CH;
    float p = 0.f, q = 0.f, o = -1e38f;
    size_t si = (size_t)b * NS * cC + c;
    float sp = stP[si], sq = stQ[si], so = stO[si];
    for (int ch = 0; ch < NS; ++ch) {
        float np_ = 0.f, nq_ = 0.f, no_ = -1e38f;
        if (ch + 1 < NS) {
            size_t sj = si + (size_t)(ch + 1) * cC;
            np_ = stP[sj]; nq_ = stQ[sj]; no_ = stO[sj];
        }
        size_t sc = si + (size_t)ch * cC;
        stP[sc] = p; stQ[sc] = q; stO[sc] = o;
        float po = o + Lw;
        float m = fmaxf(po, so);
        float e1 = __expf(po - m), e2 = __expf(so - m);
        p = e1 * p + e2 * sp;
        q = e1 * q + e2 * sq;
        o = m;
        sp = np_; sq = nq_; so = no_;
    }
}

__global__ __launch_bounds__(192) void wkv_pass3(
    const bf* __restrict__ k, const bf* __restrict__ v, const bf* __restrict__ sr,
    const float* __restrict__ sd, const float* __restrict__ sf,
    const float* __restrict__ iP, const float* __restrict__ iQ,
    const float* __restrict__ iO, bf* __restrict__ z)
{
    const int c2 = threadIdx.x % 96, sub = threadIdx.x / 96;
    const int b = blockIdx.y, ch = blockIdx.x * 2 + sub;
    const int c0 = c2 * 2;
    const float w0 = sd[c0] * Tinv, w1 = sd[c0 + 1] * Tinv;
    const float u0 = sf[c0] * Tinv, u1 = sf[c0 + 1] * Tinv;
    size_t si = ((size_t)b * NS + ch) * cC + c0;
    float2 pp = *reinterpret_cast<const float2*>(iP + si);
    float2 qq = *reinterpret_cast<const float2*>(iQ + si);
    float2 oo = *reinterpret_cast<const float2*>(iO + si);
    float p0 = pp.x, q0 = qq.x, o0 = oo.x;
    float p1 = pp.y, q1 = qq.y, o1 = oo.y;
    size_t base = ((size_t)b * cT + (size_t)ch * CH) * cC + c0;
    unsigned kwc = *reinterpret_cast<const unsigned*>(k + base);
    unsigned vwc = *reinterpret_cast<const unsigned*>(v + base);
    unsigned rwc = *reinterpret_cast<const unsigned*>(sr + base);
    for (int s = 0; s < CH; ++s) {
        unsigned kwn = 0, vwn = 0, rwn = 0;
        if (s + 1 < CH) {
            size_t nx = base + (size_t)(s + 1) * cC;
            kwn = *reinterpret_cast<const unsigned*>(k + nx);
            vwn = *reinterpret_cast<const unsigned*>(v + nx);
            rwn = *reinterpret_cast<const unsigned*>(sr + nx);
        }
        float kt0 = bflo(kwc), kt1 = bfhi(kwc);
        float vt0 = bflo(vwc), vt1 = bfhi(vwc);
        float rt0 = bflo(rwc), rt1 = bfhi(rwc);

        float no0 = fmaxf(o0, u0 + kt0);
        float Ae0 = __expf(o0 - no0), Be0 = __expf(u0 + kt0 - no0);
        float y0 = (Ae0 * p0 + Be0 * vt0) / (Ae0 * q0 + Be0);
        float no1 = fmaxf(o1, u1 + kt1);
        float Ae1 = __expf(o1 - no1), Be1 = __expf(u1 + kt1 - no1);
        float y1 = (Ae1 * p1 + Be1 * vt1) / (Ae1 * q1 + Be1);

        bf z0 = __float2bfloat16(rt0 * y0);
        bf z1 = __float2bfloat16(rt1 * y1);
        unsigned zp = (unsigned)*reinterpret_cast<unsigned short*>(&z0)
                    | ((unsigned)*reinterpret_cast<unsigned short*>(&z1) << 16);
        *reinterpret_cast<unsigned*>(z + base + (size_t)s * cC) = zp;

        float m0 = fmaxf(w0 + o0, kt0);
        float A0 = __expf(w0 + o0 - m0), B0 = __expf(kt0 - m0);
        p0 = A0 * p0 + B0 * vt0; q0 = A0 * q0 + B0; o0 = m0;
        float m1 = fmaxf(w1 + o1, kt1);
        float A1 = __expf(w1 + o1 - m1), B1 = __expf(kt1 - m1);
        p1 = A1 * p1 + B1 * vt1; q1 = A1 * q1 + B1; o1 = m1;
        kwc = kwn; vwc = vwn; rwc = rwn;
    }
}

extern "C" void kernel_launch(void* const* d_in, const int* in_sizes, int n_in,
                              void* d_out, int out_size, void* d_ws, size_t ws_size,
                              hipStream_t stream)
{
    const float* x  = (const float*)d_in[0];
    const float* Wk = (const float*)d_in[1];
    const float* Wv = (const float*)d_in[2];
    const float* Wr = (const float*)d_in[3];
    const float* Wo = (const float*)d_in[4];
    const float* sd = (const float*)d_in[5];
    const float* sf = (const float*)d_in[6];
    float* out = (float*)d_out;

    const size_t nEl = (size_t)cM * cC;          // 28,311,552 elements
    // d_out (f32, 113.2MB) holds k and sr (bf16, 2x56.6MB) until final gemm.
    bf* kbuf  = (bf*)d_out;
    bf* srbuf = (bf*)d_out + nEl;
    char* ws = (char*)d_ws;
    bf* vbuf = (bf*)ws;                           // 56.6MB
    bf* zbuf = (bf*)(ws + 2 * nEl);               // 56.6MB
    const size_t stN = (size_t)cB * NS * cC;      // 589,824 floats each
    float* stP = (float*)(ws + 4 * nEl);          // 3 x 2.36MB (in-place prefix)
    float* stQ = stP + stN;
    float* stO = stQ + stN;
    bf* wbf = (bf*)(stO + stN);                   // [Wk;Wv;Wr;Wo] bf16, 768x192

    convw_k<<<dim3(72), dim3(256), 0, stream>>>(Wk, Wv, Wr, Wo, wbf);
    gemm0f<<<dim3(256), dim3(768), 0, stream>>>(x, wbf, kbuf, vbuf, srbuf);
    wkv_pass1<<<dim3(NS / 2, cB), dim3(192), 0, stream>>>(kbuf, vbuf, sd, stP, stQ, stO);
    wkv_pass2<<<dim3(cB), dim3(192), 0, stream>>>(stP, stQ, stO, sd);
    wkv_pass3<<<dim3(NS / 2, cB), dim3(192), 0, stream>>>(
        kbuf, vbuf, srbuf, sd, sf, stP, stQ, stO, zbuf);
    gemm1g<<<dim3(256), dim3(768), 0, stream>>>(
        zbuf, wbf + (size_t)576 * cC, out);
}

// Round 20
// 214.758 us; speedup vs baseline: 1.1273x; 1.0595x over previous
//
#include <hip/hip_runtime.h>
#include <hip/hip_bf16.h>

typedef __bf16 bf16x8 __attribute__((ext_vector_type(8)));
typedef float f32x4 __attribute__((ext_vector_type(4)));

using bf = __hip_bfloat16;

constexpr int cB = 16, cH = 96, cW = 96, cC = 192;
constexpr int cT = cH * cW;       // 9216
constexpr int cM = cB * cT;       // 147456
constexpr int CH = 48;            // wkv chunk length
constexpr int NS = cT / CH;       // 192 chunks
constexpr int NTM = cM / 64;      // 2304 m-tiles
constexpr float Tinv = 1.0f / 9216.0f;

__device__ __forceinline__ int swz(int row, int bytecol) {
    return row * 384 + (bytecol ^ ((row & 7) << 4));
}
__device__ __forceinline__ float bflo(unsigned u) { return __uint_as_float(u << 16); }
__device__ __forceinline__ float bfhi(unsigned u) { return __uint_as_float(u & 0xffff0000u); }

// ---------------------------------------------------------------------------
// Pre-convert weights f32 -> bf16, concatenated rows: [Wk;Wv;Wr;Wo] (768x192)
// ---------------------------------------------------------------------------
__global__ __launch_bounds__(256) void convw_k(
    const float* __restrict__ Wk, const float* __restrict__ Wv,
    const float* __restrict__ Wr, const float* __restrict__ Wo,
    bf* __restrict__ out)
{
    int i = (blockIdx.x * 256 + threadIdx.x) * 8;
    int mat = i / 36864, off = i % 36864;
    const float* s = mat == 0 ? Wk : (mat == 1 ? Wv : (mat == 2 ? Wr : Wo));
    const float4* sp = reinterpret_cast<const float4*>(s + off);
    float4 a0 = sp[0], a1 = sp[1];
    bf16x8 pk;
    pk[0]=(__bf16)a0.x; pk[1]=(__bf16)a0.y; pk[2]=(__bf16)a0.z; pk[3]=(__bf16)a0.w;
    pk[4]=(__bf16)a1.x; pk[5]=(__bf16)a1.y; pk[6]=(__bf16)a1.z; pk[7]=(__bf16)a1.w;
    *reinterpret_cast<bf16x8*>(reinterpret_cast<__bf16*>(out) + i) = pk;
}

// ---------------------------------------------------------------------------
// gemm0f (223us-champion form): fused 3-matrix GEMM. Grid 256, 768 thr = 12
// waves; wave wid: mat = wid>>2, strip = wid&3. B fragments (own mat)
// persistent in registers; A double-buffered in LDS (2 x 24KB); per step:
// issue A-loads(i+1) -> compute(i) -> store -> ds_write(i+1) -> one barrier.
// x read once (FETCH 65MB verified); scalar [m][c] stores (WRITE 166MB clean).
// Measured ~94-95us @ 2.5 TB/s (1 block/CU regime ceiling).
// ---------------------------------------------------------------------------
__global__ __launch_bounds__(768, 3) void gemm0f(
    const float* __restrict__ Ap, const bf* __restrict__ Wb,
    bf* __restrict__ O0, bf* __restrict__ O1, bf* __restrict__ O2)
{
    __shared__ char lds[2 * 64 * 384];
    const int tid = threadIdx.x, bx = blockIdx.x;
    const int lane = tid & 63, wid = tid >> 6;
    const int mat = wid >> 2, strip = wid & 3;
    const int lr = lane & 15, lq = lane >> 4;

    bf16x8 bw[3][6];
    {
        const bf* Wt = Wb + (size_t)mat * 192 * cC;
#pragma unroll
        for (int nt = 0; nt < 3; ++nt)
#pragma unroll
            for (int kk = 0; kk < 6; ++kk)
                bw[nt][kk] = *reinterpret_cast<const bf16x8*>(
                    Wt + (size_t)(strip * 48 + nt * 16 + lr) * cC + kk * 32 + lq * 8);
    }

    int rj[2], kbj[2];
#pragma unroll
    for (int j = 0; j < 2; ++j) { int idx = tid + j * 768; rj[j] = idx / 24; kbj[j] = idx % 24; }

    float4 pfA[4];

    auto loadA = [&](int tile) {
#pragma unroll
        for (int j = 0; j < 2; ++j) {
            int gm = tile * 64 + rj[j];
            int b = gm / cT, t = gm % cT, h = t / cW, w = t % cW;
            int grp = kbj[j] / 6;
            int hs = h + (grp == 2 ? -1 : (grp == 3 ? 1 : 0));
            int ws2 = w + (grp == 0 ? -1 : (grp == 1 ? 1 : 0));
            pfA[2*j] = float4{0,0,0,0}; pfA[2*j+1] = float4{0,0,0,0};
            if (hs >= 0 && hs < cH && ws2 >= 0 && ws2 < cW) {
                const float4* s = reinterpret_cast<const float4*>(
                    Ap + ((size_t)b * cT + (size_t)hs * cW + ws2) * cC + kbj[j] * 8);
                pfA[2*j] = s[0]; pfA[2*j+1] = s[1];
            }
        }
    };
    auto writeA = [&](int bufIdx) {
        char* An = &lds[0] + bufIdx * (64 * 384);
#pragma unroll
        for (int j = 0; j < 2; ++j) {
            bf16x8 pk;
            pk[0]=(__bf16)pfA[2*j].x; pk[1]=(__bf16)pfA[2*j].y; pk[2]=(__bf16)pfA[2*j].z; pk[3]=(__bf16)pfA[2*j].w;
            pk[4]=(__bf16)pfA[2*j+1].x; pk[5]=(__bf16)pfA[2*j+1].y; pk[6]=(__bf16)pfA[2*j+1].z; pk[7]=(__bf16)pfA[2*j+1].w;
            *reinterpret_cast<bf16x8*>(An + swz(rj[j], kbj[j] * 16)) = pk;
        }
    };

    bf* Os = (mat == 0 ? O0 : (mat == 1 ? O1 : O2));

    loadA(bx); writeA(0);
    __syncthreads();

    for (int i = 0; i < 9; ++i) {
        const int tix = bx + 256 * i;
        if (i < 8) loadA(bx + 256 * (i + 1));
        char* Ab = &lds[0] + (i & 1) * (64 * 384);
#pragma unroll
        for (int mh = 0; mh < 2; ++mh) {
            f32x4 acc[2][3] = {};
#pragma unroll
            for (int kk = 0; kk < 6; ++kk) {
                const int bc = kk * 64 + lq * 16;
                bf16x8 af[2];
#pragma unroll
                for (int mt = 0; mt < 2; ++mt)
                    af[mt] = *reinterpret_cast<const bf16x8*>(
                        Ab + swz(mh * 32 + mt * 16 + lr, bc));
#pragma unroll
                for (int mt = 0; mt < 2; ++mt)
#pragma unroll
                    for (int nt = 0; nt < 3; ++nt)
                        acc[mt][nt] = __builtin_amdgcn_mfma_f32_16x16x32_bf16(
                            af[mt], bw[nt][kk], acc[mt][nt], 0, 0, 0);
            }
#pragma unroll
            for (int mt = 0; mt < 2; ++mt)
#pragma unroll
                for (int nt = 0; nt < 3; ++nt)
#pragma unroll
                    for (int j = 0; j < 4; ++j) {
                        int row = tix * 64 + mh * 32 + mt * 16 + lq * 4 + j;
                        int col = strip * 48 + nt * 16 + lr;
                        float v = acc[mt][nt][j];
                        if (mat == 2) v = 1.0f / (1.0f + __expf(-v));
                        Os[(size_t)row * cC + col] = __float2bfloat16(v);
                    }
        }
        if (i < 8) writeA((i + 1) & 1);
        __syncthreads();
    }
}

// ---------------------------------------------------------------------------
// gemm1h: out = z @ Wo^T. R16's measured-best structure (512 thr, 8 waves
// 2m x 4n, Wo in registers, grid 512 -> 2 blocks/CU) + global_load_lds DMA
// staging (16B/lane) with PRE-SWIZZLED global source:
//   LDS is written LINEARLY (wave-uniform base + lane*16, HW requirement);
//   the lane's global chunk is kb = c16 ^ (r&7), the inverse of the swz()
//   XOR, so the compute-side swizzled ds_read finds A[row][k] (rule 21).
// Double-buffered: issue DMA(next tile) before compute; the barrier's
// vmcnt(0) drain is covered by the compute phase.
// ---------------------------------------------------------------------------
__global__ __launch_bounds__(512, 4) void gemm1h(
    const bf* __restrict__ Az, const bf* __restrict__ Wb,
    float* __restrict__ Out)
{
    __shared__ char lds[2 * 64 * 384];
    const int tid = threadIdx.x, bx = blockIdx.x;
    const int lane = tid & 63, wid = tid >> 6;
    const int wm = wid >> 2, wn = wid & 3;   // 2m x 4n
    const int lr = lane & 15, lq = lane >> 4;

    bf16x8 bw[3][6];
#pragma unroll
    for (int nt = 0; nt < 3; ++nt)
#pragma unroll
        for (int kk = 0; kk < 6; ++kk)
            bw[nt][kk] = *reinterpret_cast<const bf16x8*>(
                Wb + (size_t)(wn * 48 + nt * 16 + lr) * cC + kk * 32 + lq * 8);

    // linear-LDS staging coords: chunk idx = tid + j*512 -> row r, chunk c16;
    // global source chunk is c16 ^ (r&7)  (inverse of swz's XOR)
    int rj[3], kbsrc[3];
#pragma unroll
    for (int j = 0; j < 3; ++j) {
        int idx = tid + j * 512;
        int r = idx / 24, c16 = idx % 24;
        rj[j] = r;
        kbsrc[j] = c16 ^ (r & 7);
    }

    auto stageA = [&](int tile, int bufIdx) {
        char* base = &lds[0] + bufIdx * (64 * 384);
#pragma unroll
        for (int j = 0; j < 3; ++j) {
            const bf* g = Az + (size_t)(tile * 64 + rj[j]) * cC + kbsrc[j] * 8;
            __builtin_amdgcn_global_load_lds(
                (const __attribute__((address_space(1))) void*)g,
                (__attribute__((address_space(3))) void*)(base + (tid + j * 512) * 16),
                16, 0, 0);
        }
    };

    stageA(bx, 0);
    __syncthreads();   // vmcnt(0) drain -> buf0 ready

    int step = 0;
    for (int tix = bx; tix < NTM; tix += 512, ++step) {
        if (tix + 512 < NTM) stageA(tix + 512, (step + 1) & 1);  // DMA overlaps compute
        char* Ab = &lds[0] + (step & 1) * (64 * 384);
#pragma unroll
        for (int mh = 0; mh < 2; ++mh) {     // rows wm*32 + mh*16
            f32x4 acc[3] = {};
#pragma unroll
            for (int kk = 0; kk < 6; ++kk) {
                const int bc = kk * 64 + lq * 16;
                bf16x8 af = *reinterpret_cast<const bf16x8*>(
                    Ab + swz(wm * 32 + mh * 16 + lr, bc));
#pragma unroll
                for (int nt = 0; nt < 3; ++nt)
                    acc[nt] = __builtin_amdgcn_mfma_f32_16x16x32_bf16(
                        af, bw[nt][kk], acc[nt], 0, 0, 0);
            }
#pragma unroll
            for (int nt = 0; nt < 3; ++nt)
#pragma unroll
                for (int j = 0; j < 4; ++j) {
                    int row = tix * 64 + wm * 32 + mh * 16 + lq * 4 + j;
                    int col = wn * 48 + nt * 16 + lr;
                    Out[(size_t)row * cC + col] = acc[nt][j];
                }
        }
        __syncthreads();
    }
}

// ---------------------------------------------------------------------------
// WKV (R8/R14-proven): chunked scan over [m][c] bf16, 2 channels/thread,
// CH=48 (NS=192), per-step software prefetch, in-place pass2.
// ---------------------------------------------------------------------------
__global__ __launch_bounds__(192) void wkv_pass1(
    const bf* __restrict__ k, const bf* __restrict__ v,
    const float* __restrict__ sd,
    float* __restrict__ stP, float* __restrict__ stQ, float* __restrict__ stO)
{
    const int c2 = threadIdx.x % 96, sub = threadIdx.x / 96;
    const int b = blockIdx.y, ch = blockIdx.x * 2 + sub;
    const int c0 = c2 * 2;
    const float w0 = sd[c0] * Tinv, w1 = sd[c0 + 1] * Tinv;
    size_t base = ((size_t)b * cT + (size_t)ch * CH) * cC + c0;
    float p0 = 0.f, q0 = 0.f, o0 = -1e38f;
    float p1 = 0.f, q1 = 0.f, o1 = -1e38f;
    unsigned kwc = *reinterpret_cast<const unsigned*>(k + base);
    unsigned vwc = *reinterpret_cast<const unsigned*>(v + base);
    for (int s = 0; s < CH; ++s) {
        unsigned kwn = 0, vwn = 0;
        if (s + 1 < CH) {
            kwn = *reinterpret_cast<const unsigned*>(k + base + (size_t)(s + 1) * cC);
            vwn = *reinterpret_cast<const unsigned*>(v + base + (size_t)(s + 1) * cC);
        }
        float kt0 = bflo(kwc), kt1 = bfhi(kwc);
        float vt0 = bflo(vwc), vt1 = bfhi(vwc);
        float no0 = fmaxf(w0 + o0, kt0);
        float A0 = __expf(w0 + o0 - no0), B0 = __expf(kt0 - no0);
        p0 = A0 * p0 + B0 * vt0; q0 = A0 * q0 + B0; o0 = no0;
        float no1 = fmaxf(w1 + o1, kt1);
        float A1 = __expf(w1 + o1 - no1), B1 = __expf(kt1 - no1);
        p1 = A1 * p1 + B1 * vt1; q1 = A1 * q1 + B1; o1 = no1;
        kwc = kwn; vwc = vwn;
    }
    size_t si = ((size_t)b * NS + ch) * cC + c0;
    *reinterpret_cast<float2*>(stP + si) = make_float2(p0, p1);
    *reinterpret_cast<float2*>(stQ + si) = make_float2(q0, q1);
    *reinterpret_cast<float2*>(stO + si) = make_float2(o0, o1);
}

// In-place exclusive prefix over chunk states.
__global__ __launch_bounds__(192) void wkv_pass2(
    float* __restrict__ stP, float* __restrict__ stQ, float* __restrict__ stO,
    const float* __restrict__ sd)
{
    const int c = threadIdx.x, b = blockIdx.x;
    const float w = sd[c] * Tinv;
    const float Lw = w * (float)CH;
    float p = 0.f, q = 0.f, o = -1e38f;
    size_t si = (size_t)b * NS * cC + c;
    float sp = stP[si], sq = stQ[si], so = stO[si];
    for (int ch = 0; ch < NS; ++ch) {
        float np_ = 0.f, nq_ = 0.f, no_ = -1e38f;
        if (ch + 1 < NS) {
            size_t sj = si + (size_t)(ch + 1) * cC;
            np_ = stP[sj]; nq_ = stQ[sj]; no_ = stO[sj];
        }
        size_t sc = si + (size_t)ch * cC;
        stP[sc] = p; stQ[sc] = q; stO[sc] = o;
        float po = o + Lw;
        float m = fmaxf(po, so);
        float e1 = __expf(po - m), e2 = __expf(so - m);
        p = e1 * p + e2 * sp;
        q = e1 * q + e2 * sq;
        o = m;
        sp = np_; sq = nq_; so = no_;
    }
}

__global__ __launch_bounds__(192) void wkv_pass3(
    const bf* __restrict__ k, const bf* __restrict__ v, const bf* __restrict__ sr,
    const float* __restrict__ sd, const float* __restrict__ sf,
    const float* __restrict__ iP, const float* __restrict__ iQ,
    const float* __restrict__ iO, bf* __restrict__ z)
{
    const int c2 = threadIdx.x % 96, sub = threadIdx.x / 96;
    const int b = blockIdx.y, ch = blockIdx.x * 2 + sub;
    const int c0 = c2 * 2;
    const float w0 = sd[c0] * Tinv, w1 = sd[c0 + 1] * Tinv;
    const float u0 = sf[c0] * Tinv, u1 = sf[c0 + 1] * Tinv;
    size_t si = ((size_t)b * NS + ch) * cC + c0;
    float2 pp = *reinterpret_cast<const float2*>(iP + si);
    float2 qq = *reinterpret_cast<const float2*>(iQ + si);
    float2 oo = *reinterpret_cast<const float2*>(iO + si);
    float p0 = pp.x, q0 = qq.x, o0 = oo.x;
    float p1 = pp.y, q1 = qq.y, o1 = oo.y;
    size_t base = ((size_t)b * cT + (size_t)ch * CH) * cC + c0;
    unsigned kwc = *reinterpret_cast<const unsigned*>(k + base);
    unsigned vwc = *reinterpret_cast<const unsigned*>(v + base);
    unsigned rwc = *reinterpret_cast<const unsigned*>(sr + base);
    for (int s = 0; s < CH; ++s) {
        unsigned kwn = 0, vwn = 0, rwn = 0;
        if (s + 1 < CH) {
            size_t nx = base + (size_t)(s + 1) * cC;
            kwn = *reinterpret_cast<const unsigned*>(k + nx);
            vwn = *reinterpret_cast<const unsigned*>(v + nx);
            rwn = *reinterpret_cast<const unsigned*>(sr + nx);
        }
        float kt0 = bflo(kwc), kt1 = bfhi(kwc);
        float vt0 = bflo(vwc), vt1 = bfhi(vwc);
        float rt0 = bflo(rwc), rt1 = bfhi(rwc);

        float no0 = fmaxf(o0, u0 + kt0);
        float Ae0 = __expf(o0 - no0), Be0 = __expf(u0 + kt0 - no0);
        float y0 = (Ae0 * p0 + Be0 * vt0) / (Ae0 * q0 + Be0);
        float no1 = fmaxf(o1, u1 + kt1);
        float Ae1 = __expf(o1 - no1), Be1 = __expf(u1 + kt1 - no1);
        float y1 = (Ae1 * p1 + Be1 * vt1) / (Ae1 * q1 + Be1);

        bf z0 = __float2bfloat16(rt0 * y0);
        bf z1 = __float2bfloat16(rt1 * y1);
        unsigned zp = (unsigned)*reinterpret_cast<unsigned short*>(&z0)
                    | ((unsigned)*reinterpret_cast<unsigned short*>(&z1) << 16);
        *reinterpret_cast<unsigned*>(z + base + (size_t)s * cC) = zp;

        float m0 = fmaxf(w0 + o0, kt0);
        float A0 = __expf(w0 + o0 - m0), B0 = __expf(kt0 - m0);
        p0 = A0 * p0 + B0 * vt0; q0 = A0 * q0 + B0; o0 = m0;
        float m1 = fmaxf(w1 + o1, kt1);
        float A1 = __expf(w1 + o1 - m1), B1 = __expf(kt1 - m1);
        p1 = A1 * p1 + B1 * vt1; q1 = A1 * q1 + B1; o1 = m1;
        kwc = kwn; vwc = vwn; rwc = rwn;
    }
}

extern "C" void kernel_launch(void* const* d_in, const int* in_sizes, int n_in,
                              void* d_out, int out_size, void* d_ws, size_t ws_size,
                              hipStream_t stream)
{
    const float* x  = (const float*)d_in[0];
    const float* Wk = (const float*)d_in[1];
    const float* Wv = (const float*)d_in[2];
    const float* Wr = (const float*)d_in[3];
    const float* Wo = (const float*)d_in[4];
    const float* sd = (const float*)d_in[5];
    const float* sf = (const float*)d_in[6];
    float* out = (float*)d_out;

    const size_t nEl = (size_t)cM * cC;          // 28,311,552 elements
    // d_out (f32, 113.2MB) holds k and sr (bf16, 2x56.6MB) until final gemm.
    bf* kbuf  = (bf*)d_out;
    bf* srbuf = (bf*)d_out + nEl;
    char* ws = (char*)d_ws;
    bf* vbuf = (bf*)ws;                           // 56.6MB
    bf* zbuf = (bf*)(ws + 2 * nEl);               // 56.6MB
    const size_t stN = (size_t)cB * NS * cC;      // 589,824 floats each
    float* stP = (float*)(ws + 4 * nEl);          // 3 x 2.36MB (in-place prefix)
    float* stQ = stP + stN;
    float* stO = stQ + stN;
    bf* wbf = (bf*)(stO + stN);                   // [Wk;Wv;Wr;Wo] bf16, 768x192

    convw_k<<<dim3(72), dim3(256), 0, stream>>>(Wk, Wv, Wr, Wo, wbf);
    gemm0f<<<dim3(256), dim3(768), 0, stream>>>(x, wbf, kbuf, vbuf, srbuf);
    wkv_pass1<<<dim3(NS / 2, cB), dim3(192), 0, stream>>>(kbuf, vbuf, sd, stP, stQ, stO);
    wkv_pass2<<<dim3(cB), dim3(192), 0, stream>>>(stP, stQ, stO, sd);
    wkv_pass3<<<dim3(NS / 2, cB), dim3(192), 0, stream>>>(
        kbuf, vbuf, srbuf, sd, sf, stP, stQ, stO, zbuf);
    gemm1h<<<dim3(512), dim3(512), 0, stream>>>(
        zbuf, wbf + (size_t)576 * cC, out);
}